// Round 1
// baseline (1069.592 us; speedup 1.0000x reference)
//
#include <hip/hip_runtime.h>
#include <hip/hip_bf16.h>
#include <math.h>

// GQA forward, fp32 baseline (round 1: correctness + counters).
// Pipeline: [gemm x3 -> packed QKV T[4096][1536]] -> [rmsnorm+rope Q,K] ->
//           [flash attention -> O[4096][1024]] -> [proj gemm -> d_out]
// ws usage: T (24 MB) + O (16 MB) = 40 MB.

#define N_SEQ 2048
#define EMB   1024
#define NH    16
#define NKV   4
#define HD    64
#define BATCH 2
#define M_TOT (BATCH * N_SEQ)   // 4096
#define TCOLS 1536              // 1024 Q + 256 K + 256 V

// ---------------------------------------------------------------------------
// Generic tiled GEMM: C[m][n] = sum_k A[m][k] * W[n][k] + bias[n]
// A: [M][K] row-major, W: [N][K] row-major (i.e. torch-style weight),
// C row stride = ldc. Tile 64x64, BK=16, 256 threads, 4x4 micro-tile.
// All dims divisible by tile sizes (M=4096, N in {1024,256}, K=1024).
// ---------------------------------------------------------------------------
__global__ __launch_bounds__(256) void gemm_bias_kernel(
    const float* __restrict__ A, const float* __restrict__ W,
    const float* __restrict__ bias, float* __restrict__ C,
    int K, int ldc)
{
    __shared__ float As[16][68];   // [k][m], padded
    __shared__ float Bs[16][68];   // [k][n], padded

    const int tid = threadIdx.x;
    const int m0 = blockIdx.y * 64;
    const int n0 = blockIdx.x * 64;

    const int row = tid >> 2;          // 0..63
    const int kc  = (tid & 3) << 2;    // 0,4,8,12

    const float* Ap = A + (size_t)(m0 + row) * K + kc;
    const float* Wp = W + (size_t)(n0 + row) * K + kc;

    const int tx = tid & 15;           // n-tile coord
    const int ty = tid >> 4;           // m-tile coord

    float acc[4][4] = {{0.f}};

    for (int k0 = 0; k0 < K; k0 += 16) {
        float4 a4 = *(const float4*)(Ap + k0);
        float4 b4 = *(const float4*)(Wp + k0);
        __syncthreads();               // prior tile's reads complete
        As[kc + 0][row] = a4.x; As[kc + 1][row] = a4.y;
        As[kc + 2][row] = a4.z; As[kc + 3][row] = a4.w;
        Bs[kc + 0][row] = b4.x; Bs[kc + 1][row] = b4.y;
        Bs[kc + 2][row] = b4.z; Bs[kc + 3][row] = b4.w;
        __syncthreads();
#pragma unroll
        for (int k = 0; k < 16; ++k) {
            const float4 av = *(const float4*)&As[k][ty << 2];
            const float4 bv = *(const float4*)&Bs[k][tx << 2];
            const float a[4] = {av.x, av.y, av.z, av.w};
            const float b[4] = {bv.x, bv.y, bv.z, bv.w};
#pragma unroll
            for (int i = 0; i < 4; ++i)
#pragma unroll
                for (int j = 0; j < 4; ++j)
                    acc[i][j] = fmaf(a[i], b[j], acc[i][j]);
        }
    }

    const float4 bb = *(const float4*)(bias + n0 + (tx << 2));
#pragma unroll
    for (int i = 0; i < 4; ++i) {
        float4 o;
        o.x = acc[i][0] + bb.x;
        o.y = acc[i][1] + bb.y;
        o.z = acc[i][2] + bb.z;
        o.w = acc[i][3] + bb.w;
        *(float4*)(C + (size_t)(m0 + (ty << 2) + i) * ldc + n0 + (tx << 2)) = o;
    }
}

// ---------------------------------------------------------------------------
// RMSNorm (over D=64) + RoPE, one wave (64 lanes) per head-vector, in place.
// hshift: log2(heads per token row). colBase: column offset inside T row.
// ---------------------------------------------------------------------------
__global__ __launch_bounds__(256) void norm_rope_kernel(
    float* __restrict__ T, int colBase, int hshift,
    const float* __restrict__ w, const float* __restrict__ sinp,
    const float* __restrict__ cosp, int numVecs)
{
    const int vec  = (int)((blockIdx.x * blockDim.x + threadIdx.x) >> 6);
    const int lane = threadIdx.x & 63;
    if (vec >= numVecs) return;

    const int m = vec >> hshift;              // token row 0..4095
    const int h = vec & ((1 << hshift) - 1);  // head index
    const int n = m & (N_SEQ - 1);            // position in sequence

    float* p = T + (size_t)m * TCOLS + colBase + h * HD;
    const float t = p[lane];

    float s = t * t;
#pragma unroll
    for (int mask = 32; mask; mask >>= 1) s += __shfl_xor(s, mask, 64);
    const float r = rsqrtf(s * (1.0f / 64.0f) + 1e-6f);

    const float tn = t * r * w[lane];
    const float partner = __shfl_xor(tn, 32, 64);
    const float rot = (lane < 32) ? -partner : partner;

    p[lane] = tn * cosp[n * HD + lane] + rot * sinp[n * HD + lane];
}

// ---------------------------------------------------------------------------
// Flash attention, fp32. Block: 64 q-rows of one (b,h); loops 32 k-tiles of 64.
// LDS: Qs/Ks transposed [d][row], Vs natural [key][d], Ps transposed [key][row].
// 256 threads as 16x16, each thread 4x4 of S (rows x keys) and 4x4 of O
// (rows x dims). Online softmax state (m,l) per row, replicated over the
// 16-lane row group via shuffles.
// ---------------------------------------------------------------------------
__global__ __launch_bounds__(256) void flash_attn_kernel(
    const float* __restrict__ T, float* __restrict__ O)
{
    const int qt = blockIdx.x;                 // 0..31
    const int bh = blockIdx.y;                 // 0..31
    const int b = bh >> 4, h = bh & 15;
    const int kvh = h >> 2;                    // GQA: repeat_interleave -> h/4

    const float* Qg = T + (size_t)b * N_SEQ * TCOLS + h * HD;
    const float* Kg = T + (size_t)b * N_SEQ * TCOLS + EMB + kvh * HD;
    const float* Vg = T + (size_t)b * N_SEQ * TCOLS + EMB + NKV * HD + kvh * HD;
    float* Og = O + (size_t)b * N_SEQ * EMB + h * HD;

    __shared__ float Qs[64][68];   // [d][row]
    __shared__ float Ks[64][68];   // [d][key]
    __shared__ float Vs[64][68];   // [key][d]
    __shared__ float Ps[64][68];   // [key][row]

    const int tid = threadIdx.x;
    const int tx = tid & 15;       // key group (S) / dim group (O)
    const int ty = tid >> 4;       // row group

    // stage Q once
#pragma unroll
    for (int it = 0; it < 4; ++it) {
        const int idx = tid + it * 256;            // 0..1023
        const int r = idx >> 4;
        const int dc = (idx & 15) << 2;
        const float4 q4 = *(const float4*)(Qg + (size_t)(qt * 64 + r) * TCOLS + dc);
        Qs[dc + 0][r] = q4.x; Qs[dc + 1][r] = q4.y;
        Qs[dc + 2][r] = q4.z; Qs[dc + 3][r] = q4.w;
    }

    float o[4][4] = {{0.f}};
    float mrow[4], lrow[4];
#pragma unroll
    for (int i = 0; i < 4; ++i) { mrow[i] = -1e30f; lrow[i] = 0.f; }

    for (int kt = 0; kt < N_SEQ / 64; ++kt) {
        // stage K,V tile
        float4 kreg[4], vreg[4];
#pragma unroll
        for (int it = 0; it < 4; ++it) {
            const int idx = tid + it * 256;
            const int r = idx >> 4;
            const int dc = (idx & 15) << 2;
            kreg[it] = *(const float4*)(Kg + (size_t)(kt * 64 + r) * TCOLS + dc);
            vreg[it] = *(const float4*)(Vg + (size_t)(kt * 64 + r) * TCOLS + dc);
        }
        __syncthreads();   // prior tile's PV reads (and Q staging) complete
#pragma unroll
        for (int it = 0; it < 4; ++it) {
            const int idx = tid + it * 256;
            const int r = idx >> 4;
            const int dc = (idx & 15) << 2;
            Ks[dc + 0][r] = kreg[it].x; Ks[dc + 1][r] = kreg[it].y;
            Ks[dc + 2][r] = kreg[it].z; Ks[dc + 3][r] = kreg[it].w;
            *(float4*)&Vs[r][dc] = vreg[it];
        }
        __syncthreads();

        // S = Q K^T (4x4 per thread), reduction over d
        float s[4][4] = {{0.f}};
#pragma unroll 8
        for (int d = 0; d < 64; ++d) {
            const float4 av = *(const float4*)&Qs[d][ty << 2];
            const float4 bv = *(const float4*)&Ks[d][tx << 2];
            const float a[4] = {av.x, av.y, av.z, av.w};
            const float bb[4] = {bv.x, bv.y, bv.z, bv.w};
#pragma unroll
            for (int i = 0; i < 4; ++i)
#pragma unroll
                for (int j = 0; j < 4; ++j)
                    s[i][j] = fmaf(a[i], bb[j], s[i][j]);
        }

        // online softmax (scale 1/sqrt(64) = 0.125)
#pragma unroll
        for (int i = 0; i < 4; ++i) {
#pragma unroll
            for (int j = 0; j < 4; ++j) s[i][j] *= 0.125f;
            float mx = fmaxf(fmaxf(s[i][0], s[i][1]), fmaxf(s[i][2], s[i][3]));
#pragma unroll
            for (int mask = 1; mask <= 8; mask <<= 1)
                mx = fmaxf(mx, __shfl_xor(mx, mask, 64));
            const float mnew = fmaxf(mrow[i], mx);
            const float alpha = __expf(mrow[i] - mnew);
            mrow[i] = mnew;
            float rs = 0.f;
#pragma unroll
            for (int j = 0; j < 4; ++j) {
                s[i][j] = __expf(s[i][j] - mnew);
                rs += s[i][j];
            }
#pragma unroll
            for (int mask = 1; mask <= 8; mask <<= 1)
                rs += __shfl_xor(rs, mask, 64);
            lrow[i] = lrow[i] * alpha + rs;
#pragma unroll
            for (int d = 0; d < 4; ++d) o[i][d] *= alpha;
        }

        // P -> LDS (transposed [key][row])
#pragma unroll
        for (int i = 0; i < 4; ++i)
#pragma unroll
            for (int j = 0; j < 4; ++j)
                Ps[(tx << 2) + j][(ty << 2) + i] = s[i][j];
        __syncthreads();

        // O += P V (reduction over keys j)
#pragma unroll 8
        for (int j = 0; j < 64; ++j) {
            const float4 pv = *(const float4*)&Ps[j][ty << 2];
            const float4 vv = *(const float4*)&Vs[j][tx << 2];
            const float p[4] = {pv.x, pv.y, pv.z, pv.w};
            const float v[4] = {vv.x, vv.y, vv.z, vv.w};
#pragma unroll
            for (int i = 0; i < 4; ++i)
#pragma unroll
                for (int d = 0; d < 4; ++d)
                    o[i][d] = fmaf(p[i], v[d], o[i][d]);
        }
    }

    // epilogue: O / l, store
#pragma unroll
    for (int i = 0; i < 4; ++i) {
        const float inv = 1.0f / lrow[i];
        float4 ov;
        ov.x = o[i][0] * inv; ov.y = o[i][1] * inv;
        ov.z = o[i][2] * inv; ov.w = o[i][3] * inv;
        *(float4*)(Og + (size_t)(qt * 64 + (ty << 2) + i) * EMB + (tx << 2)) = ov;
    }
}

// ---------------------------------------------------------------------------
extern "C" void kernel_launch(void* const* d_in, const int* in_sizes, int n_in,
                              void* d_out, int out_size, void* d_ws, size_t ws_size,
                              hipStream_t stream)
{
    const float* x      = (const float*)d_in[0];
    const float* sinp   = (const float*)d_in[1];
    const float* cosp   = (const float*)d_in[2];
    const float* wq_w   = (const float*)d_in[3];
    const float* wq_b   = (const float*)d_in[4];
    const float* wk_w   = (const float*)d_in[5];
    const float* wk_b   = (const float*)d_in[6];
    const float* wv_w   = (const float*)d_in[7];
    const float* wv_b   = (const float*)d_in[8];
    const float* qn_w   = (const float*)d_in[9];
    const float* kn_w   = (const float*)d_in[10];
    const float* proj_w = (const float*)d_in[11];
    const float* proj_b = (const float*)d_in[12];
    float* out = (float*)d_out;

    float* T = (float*)d_ws;                      // [4096][1536]
    float* O = T + (size_t)M_TOT * TCOLS;         // [4096][1024]

    const dim3 blk(256);

    // QKV projections into packed T
    gemm_bias_kernel<<<dim3(EMB / 64, M_TOT / 64), blk, 0, stream>>>(
        x, wq_w, wq_b, T, EMB, TCOLS);
    gemm_bias_kernel<<<dim3(256 / 64, M_TOT / 64), blk, 0, stream>>>(
        x, wk_w, wk_b, T + EMB, EMB, TCOLS);
    gemm_bias_kernel<<<dim3(256 / 64, M_TOT / 64), blk, 0, stream>>>(
        x, wv_w, wv_b, T + EMB + NKV * HD, EMB, TCOLS);

    // RMSNorm + RoPE on Q (16 heads/row) and K (4 heads/row)
    norm_rope_kernel<<<dim3(M_TOT * NH / 4), blk, 0, stream>>>(
        T, 0, 4, qn_w, sinp, cosp, M_TOT * NH);
    norm_rope_kernel<<<dim3(M_TOT * NKV / 4), blk, 0, stream>>>(
        T, EMB, 2, kn_w, sinp, cosp, M_TOT * NKV);

    // attention
    flash_attn_kernel<<<dim3(N_SEQ / 64, BATCH * NH), blk, 0, stream>>>(T, O);

    // output projection
    gemm_bias_kernel<<<dim3(EMB / 64, M_TOT / 64), blk, 0, stream>>>(
        O, proj_w, proj_b, out, EMB, EMB);
}

// Round 2
// 288.950 us; speedup vs baseline: 3.7017x; 3.7017x over previous
//
#include <hip/hip_runtime.h>
#include <hip/hip_bf16.h>
#include <math.h>

// GQA forward, bf16 MFMA everywhere (round 2).
// convert+pack -> QKV GEMM(mfma) -> norm+rope(Q*0.125) -> V transpose ->
// flash attention (mfma QK^T + PV, P via LDS) -> proj GEMM(mfma) -> f32 out.

#define N_SEQ 2048
#define EMB   1024
#define NH    16
#define NKV   4
#define HD    64
#define BATCH 2
#define M_TOT 4096
#define QKV_N 1536

typedef __attribute__((ext_vector_type(8))) short short8;   // 8 bf16 = 4 VGPRs
typedef __attribute__((ext_vector_type(4))) float f32x4;

__device__ __forceinline__ ushort f2bf(float f) {
    union { __hip_bfloat16 h; ushort u; } cv;
    cv.h = __float2bfloat16(f);
    return cv.u;
}
__device__ __forceinline__ float bf2f(ushort u) {
    union { __hip_bfloat16 h; ushort u; } cv;
    cv.u = u;
    return __bfloat162float(cv.h);
}

// ---------------------------------------------------------------------------
// fp32 -> bf16 convert, 4 elements/thread
// ---------------------------------------------------------------------------
__global__ __launch_bounds__(256) void cvt_bf16_kernel(
    const float* __restrict__ src, ushort* __restrict__ dst, int n4)
{
    const int i = blockIdx.x * 256 + threadIdx.x;
    if (i >= n4) return;
    const float4 v = ((const float4*)src)[i];
    ushort4 o;
    o.x = f2bf(v.x); o.y = f2bf(v.y); o.z = f2bf(v.z); o.w = f2bf(v.w);
    ((ushort4*)dst)[i] = o;
}

__global__ __launch_bounds__(256) void pack_bias_kernel(
    const float* __restrict__ q, const float* __restrict__ k,
    const float* __restrict__ v, float* __restrict__ dst)
{
    const int i = blockIdx.x * 256 + threadIdx.x;
    if (i < 1024) dst[i] = q[i];
    else if (i < 1280) dst[i] = k[i - 1024];
    else if (i < 1536) dst[i] = v[i - 1280];
}

// ---------------------------------------------------------------------------
// bf16 MFMA GEMM: C[m][n] = sum_k A[m][k]*W[n][k] + bias[n]
// A:[M][K] bf16, W:[N][K] bf16 row-major. Tile 128x128, BK=32, 256 thr = 4
// waves (2x2), each wave 64x64 = 4x4 mfma_f32_16x16x32_bf16 tiles.
// LDS rows padded to 40 shorts (80 B): frag ds_read_b128 conflict-free-ish.
// ---------------------------------------------------------------------------
template <bool BF16OUT>
__global__ __launch_bounds__(256) void gemm_mfma_kernel(
    const ushort* __restrict__ A, const ushort* __restrict__ W,
    const float* __restrict__ bias, void* __restrict__ Cout,
    int K, int ldc)
{
    __shared__ ushort As[128 * 40];
    __shared__ ushort Bs[128 * 40];

    const int tid = threadIdx.x;
    const int m0 = blockIdx.y * 128, n0 = blockIdx.x * 128;
    const int w = tid >> 6, lane = tid & 63;
    const int quad = lane >> 4, l16 = lane & 15;
    const int wm = (w & 1) * 64, wn = (w >> 1) * 64;

    f32x4 acc[4][4] = {};

    float bb[4];
#pragma unroll
    for (int j = 0; j < 4; ++j) bb[j] = bias[n0 + wn + j * 16 + l16];

    const int r0 = tid >> 2;         // staging row 0..63
    const int c0 = tid & 3;          // 8-elem chunk within BK=32
    const ushort* Ap = A + (size_t)(m0 + r0) * K + c0 * 8;
    const ushort* Wp = W + (size_t)(n0 + r0) * K + c0 * 8;

    for (int k0 = 0; k0 < K; k0 += 32) {
        const short8 a0 = *(const short8*)(Ap + k0);
        const short8 a1 = *(const short8*)(Ap + (size_t)64 * K + k0);
        const short8 b0 = *(const short8*)(Wp + k0);
        const short8 b1 = *(const short8*)(Wp + (size_t)64 * K + k0);
        __syncthreads();
        *(short8*)&As[r0 * 40 + c0 * 8] = a0;
        *(short8*)&As[(r0 + 64) * 40 + c0 * 8] = a1;
        *(short8*)&Bs[r0 * 40 + c0 * 8] = b0;
        *(short8*)&Bs[(r0 + 64) * 40 + c0 * 8] = b1;
        __syncthreads();

        short8 aF[4], bF[4];
#pragma unroll
        for (int i = 0; i < 4; ++i)
            aF[i] = *(const short8*)&As[(wm + i * 16 + l16) * 40 + quad * 8];
#pragma unroll
        for (int j = 0; j < 4; ++j)
            bF[j] = *(const short8*)&Bs[(wn + j * 16 + l16) * 40 + quad * 8];
#pragma unroll
        for (int i = 0; i < 4; ++i)
#pragma unroll
            for (int j = 0; j < 4; ++j)
                acc[i][j] = __builtin_amdgcn_mfma_f32_16x16x32_bf16(
                    aF[i], bF[j], acc[i][j], 0, 0, 0);
    }

#pragma unroll
    for (int i = 0; i < 4; ++i) {
        const int rowb = m0 + wm + i * 16 + quad * 4;
#pragma unroll
        for (int j = 0; j < 4; ++j) {
            const int col = n0 + wn + j * 16 + l16;
#pragma unroll
            for (int r = 0; r < 4; ++r) {
                const float vv = acc[i][j][r] + bb[j];
                if (BF16OUT)
                    ((ushort*)Cout)[(size_t)(rowb + r) * ldc + col] = f2bf(vv);
                else
                    ((float*)Cout)[(size_t)(rowb + r) * ldc + col] = vv;
            }
        }
    }
}

// ---------------------------------------------------------------------------
// RMSNorm(D=64) + RoPE, one wave per head-vector. Reads packed bf16 Tq,
// writes head-major bf16 dst[(b*heads + h)*N + n][d]. outScale folds the
// attention 1/sqrt(D) into Q.
// ---------------------------------------------------------------------------
__global__ __launch_bounds__(256) void norm_rope_kernel(
    const ushort* __restrict__ Tq, int colBase, int hshift,
    const float* __restrict__ nw, const float* __restrict__ sinp,
    const float* __restrict__ cosp, ushort* __restrict__ dst, float outScale)
{
    const int vec  = (int)((blockIdx.x * 256u + threadIdx.x) >> 6);
    const int lane = threadIdx.x & 63;
    const int m = vec >> hshift;
    const int h = vec & ((1 << hshift) - 1);
    const int n = m & (N_SEQ - 1);
    const int b = m >> 11;

    const float t = bf2f(Tq[(size_t)m * QKV_N + colBase + h * HD + lane]);
    float s = t * t;
#pragma unroll
    for (int mask = 32; mask; mask >>= 1) s += __shfl_xor(s, mask, 64);
    const float r = rsqrtf(s * (1.0f / 64.0f) + 1e-6f);

    const float tn = t * r * nw[lane];
    const float partner = __shfl_xor(tn, 32, 64);
    const float rot = (lane < 32) ? -partner : partner;
    const float val = (tn * cosp[n * HD + lane] + rot * sinp[n * HD + lane]) * outScale;

    dst[((size_t)((b << hshift) + h) * N_SEQ + n) * HD + lane] = f2bf(val);
}

// ---------------------------------------------------------------------------
// V: Tq [m][1280 + kv*64 + d] -> Vt [(b*KV+kv)*64 + d][n]  (64x64 LDS tiles)
// ---------------------------------------------------------------------------
__global__ __launch_bounds__(256) void transpose_v_kernel(
    const ushort* __restrict__ Tq, ushort* __restrict__ Vt)
{
    __shared__ ushort L[64 * 72];
    const int n0 = blockIdx.x * 64;
    const int bkv = blockIdx.y;
    const int b = bkv >> 2, kv = bkv & 3;
    const int tid = threadIdx.x;

#pragma unroll
    for (int it = 0; it < 2; ++it) {
        const int j = tid + it * 256;
        const int r = j >> 3, c = j & 7;
        const short8 v = *(const short8*)&Tq[(size_t)(b * N_SEQ + n0 + r) * QKV_N
                                             + 1280 + kv * HD + c * 8];
        *(short8*)&L[r * 72 + c * 8] = v;
    }
    __syncthreads();
#pragma unroll
    for (int it = 0; it < 2; ++it) {
        const int j = tid + it * 256;
        const int d = j >> 3, c = j & 7;
        short8 o;
#pragma unroll
        for (int e = 0; e < 8; ++e) o[e] = (short)L[(c * 8 + e) * 72 + d];
        *(short8*)&Vt[((size_t)(bkv * HD + d)) * N_SEQ + n0 + c * 8] = o;
    }
}

// ---------------------------------------------------------------------------
// MFMA flash attention. Block = 64 q-rows of one (b,h); 4 waves, wave w owns
// rows w*16..w*16+15. K-tiles of 64 keys. Q A-frags live in regs (scale
// pre-folded). S via 2 mfma per 16-key col-tile; online softmax on C-layout;
// P written bf16 into the Ks region (after a barrier - Ks is dead by then),
// re-read as A-frags; PV via mfma with V^T-resident LDS.
// LDS rows stride 72 shorts (144 B): 16B-aligned frags, 2-way conflicts max.
// ---------------------------------------------------------------------------
__global__ __launch_bounds__(256, 4) void flash_mfma_kernel(
    const ushort* __restrict__ Qb, const ushort* __restrict__ Kb,
    const ushort* __restrict__ Vt, ushort* __restrict__ Ob)
{
    __shared__ ushort Ks[64 * 72];
    __shared__ ushort Vs[64 * 72];

    const int qt = blockIdx.x;            // 0..31
    const int bh = blockIdx.y;            // b*16+h
    const int b = bh >> 4, h = bh & 15;
    const int kvh = h >> 2;
    const int tid = threadIdx.x;
    const int w = tid >> 6, lane = tid & 63;
    const int quad = lane >> 4, l16 = lane & 15;

    const ushort* Qg = Qb + ((size_t)bh * N_SEQ + qt * 64 + w * 16) * HD;
    const ushort* Kg = Kb + ((size_t)(b * NKV + kvh) * N_SEQ) * HD;
    const ushort* Vg = Vt + ((size_t)(b * NKV + kvh) * HD) * N_SEQ;

    short8 qF[2];
#pragma unroll
    for (int s = 0; s < 2; ++s)
        qF[s] = *(const short8*)&Qg[(size_t)l16 * HD + s * 32 + quad * 8];

    f32x4 o[4] = {};
    float mrow[4], lrow[4];
#pragma unroll
    for (int r = 0; r < 4; ++r) { mrow[r] = -1e30f; lrow[r] = 0.f; }

    ushort* Psw = Ks + w * (16 * 72);

    for (int kt = 0; kt < N_SEQ / 64; ++kt) {
        const int j0 = tid, j1 = tid + 256;
        const short8 k0 = *(const short8*)&Kg[(size_t)(kt * 64 + (j0 >> 3)) * HD + (j0 & 7) * 8];
        const short8 k1 = *(const short8*)&Kg[(size_t)(kt * 64 + (j1 >> 3)) * HD + (j1 & 7) * 8];
        const short8 v0 = *(const short8*)&Vg[(size_t)(j0 >> 3) * N_SEQ + kt * 64 + (j0 & 7) * 8];
        const short8 v1 = *(const short8*)&Vg[(size_t)(j1 >> 3) * N_SEQ + kt * 64 + (j1 & 7) * 8];
        __syncthreads();                       // prior tile's P/V reads done
        *(short8*)&Ks[(j0 >> 3) * 72 + (j0 & 7) * 8] = k0;
        *(short8*)&Ks[(j1 >> 3) * 72 + (j1 & 7) * 8] = k1;
        *(short8*)&Vs[(j0 >> 3) * 72 + (j0 & 7) * 8] = v0;
        *(short8*)&Vs[(j1 >> 3) * 72 + (j1 & 7) * 8] = v1;
        __syncthreads();                       // staging visible

        // S = Q K^T  (rows = wave's 16 q-rows, 64 keys in 4 col-tiles)
        f32x4 sA[4];
#pragma unroll
        for (int c = 0; c < 4; ++c) {
            const short8 kf0 = *(const short8*)&Ks[(c * 16 + l16) * 72 + quad * 8];
            const short8 kf1 = *(const short8*)&Ks[(c * 16 + l16) * 72 + 32 + quad * 8];
            f32x4 z = {};
            z = __builtin_amdgcn_mfma_f32_16x16x32_bf16(qF[0], kf0, z, 0, 0, 0);
            sA[c] = __builtin_amdgcn_mfma_f32_16x16x32_bf16(qF[1], kf1, z, 0, 0, 0);
        }

        __syncthreads();                       // all waves done reading Ks

        // online softmax + P -> LDS (bf16, A-layout rows)
#pragma unroll
        for (int r = 0; r < 4; ++r) {
            const float s0 = sA[0][r], s1 = sA[1][r], s2 = sA[2][r], s3 = sA[3][r];
            float mx = fmaxf(fmaxf(s0, s1), fmaxf(s2, s3));
#pragma unroll
            for (int mask = 1; mask <= 8; mask <<= 1)
                mx = fmaxf(mx, __shfl_xor(mx, mask, 64));
            const float mnew = fmaxf(mrow[r], mx);
            const float alpha = __expf(mrow[r] - mnew);
            mrow[r] = mnew;
            const float p0 = __expf(s0 - mnew), p1 = __expf(s1 - mnew);
            const float p2 = __expf(s2 - mnew), p3 = __expf(s3 - mnew);
            float rs = (p0 + p1) + (p2 + p3);
#pragma unroll
            for (int mask = 1; mask <= 8; mask <<= 1)
                rs += __shfl_xor(rs, mask, 64);
            lrow[r] = lrow[r] * alpha + rs;
            o[0][r] *= alpha; o[1][r] *= alpha; o[2][r] *= alpha; o[3][r] *= alpha;
            const int pr = (quad * 4 + r) * 72 + l16;
            Psw[pr]      = f2bf(p0);
            Psw[pr + 16] = f2bf(p1);
            Psw[pr + 32] = f2bf(p2);
            Psw[pr + 48] = f2bf(p3);
        }

        // O += P V  (wave-local P; lgkm waits inserted by compiler)
        const short8 pF0 = *(const short8*)&Psw[l16 * 72 + quad * 8];
        const short8 pF1 = *(const short8*)&Psw[l16 * 72 + 32 + quad * 8];
#pragma unroll
        for (int c = 0; c < 4; ++c) {
            const short8 vf0 = *(const short8*)&Vs[(c * 16 + l16) * 72 + quad * 8];
            const short8 vf1 = *(const short8*)&Vs[(c * 16 + l16) * 72 + 32 + quad * 8];
            o[c] = __builtin_amdgcn_mfma_f32_16x16x32_bf16(pF0, vf0, o[c], 0, 0, 0);
            o[c] = __builtin_amdgcn_mfma_f32_16x16x32_bf16(pF1, vf1, o[c], 0, 0, 0);
        }
    }

    // epilogue: normalize, write bf16 Ob [b][n][h*64+d]
    const int n = qt * 64 + w * 16 + quad * 4;
#pragma unroll
    for (int r = 0; r < 4; ++r) {
        const float inv = 1.0f / lrow[r];
        const size_t base = ((size_t)b * N_SEQ + n + r) * EMB + h * HD;
#pragma unroll
        for (int c = 0; c < 4; ++c)
            Ob[base + c * 16 + l16] = f2bf(o[c][r] * inv);
    }
}

// ---------------------------------------------------------------------------
extern "C" void kernel_launch(void* const* d_in, const int* in_sizes, int n_in,
                              void* d_out, int out_size, void* d_ws, size_t ws_size,
                              hipStream_t stream)
{
    const float* x      = (const float*)d_in[0];
    const float* sinp   = (const float*)d_in[1];
    const float* cosp   = (const float*)d_in[2];
    const float* wq_w   = (const float*)d_in[3];
    const float* wq_b   = (const float*)d_in[4];
    const float* wk_w   = (const float*)d_in[5];
    const float* wk_b   = (const float*)d_in[6];
    const float* wv_w   = (const float*)d_in[7];
    const float* wv_b   = (const float*)d_in[8];
    const float* qn_w   = (const float*)d_in[9];
    const float* kn_w   = (const float*)d_in[10];
    const float* proj_w = (const float*)d_in[11];
    const float* proj_b = (const float*)d_in[12];
    float* out = (float*)d_out;

    // workspace layout (ushort elements) — ~37 MB total
    ushort* Tq    = (ushort*)d_ws;            // 4096*1536
    ushort* xb    = Tq + 6291456;             // 4096*1024 (later reused as Ob)
    ushort* Wqkv  = xb + 4194304;             // 1536*1024
    ushort* Wproj = Wqkv + 1572864;           // 1024*1024
    float*  bqkv  = (float*)(Wproj + 1048576);// 1536
    ushort* Qb    = (ushort*)(bqkv + 1536);   // 2*16*2048*64
    ushort* Kb    = Qb + 4194304;             // 2*4*2048*64
    ushort* Vt    = Kb + 1048576;             // 2*4*64*2048

    cvt_bf16_kernel<<<4096, 256, 0, stream>>>(x, xb, 1048576);
    cvt_bf16_kernel<<<1024, 256, 0, stream>>>(wq_w, Wqkv, 262144);
    cvt_bf16_kernel<<<256, 256, 0, stream>>>(wk_w, Wqkv + 1048576, 65536);
    cvt_bf16_kernel<<<256, 256, 0, stream>>>(wv_w, Wqkv + 1310720, 65536);
    cvt_bf16_kernel<<<1024, 256, 0, stream>>>(proj_w, Wproj, 262144);
    pack_bias_kernel<<<6, 256, 0, stream>>>(wq_b, wk_b, wv_b, bqkv);

    // QKV GEMM -> Tq bf16 [4096][1536]
    gemm_mfma_kernel<true><<<dim3(QKV_N / 128, M_TOT / 128), 256, 0, stream>>>(
        xb, Wqkv, bqkv, Tq, EMB, QKV_N);

    // norm + rope (Q scaled by 1/sqrt(64))
    norm_rope_kernel<<<16384, 256, 0, stream>>>(Tq, 0, 4, qn_w, sinp, cosp, Qb, 0.125f);
    norm_rope_kernel<<<4096, 256, 0, stream>>>(Tq, EMB, 2, kn_w, sinp, cosp, Kb, 1.0f);

    transpose_v_kernel<<<dim3(32, 8), 256, 0, stream>>>(Tq, Vt);

    // attention -> Ob (= xb buffer) bf16 [4096][1024]
    flash_mfma_kernel<<<dim3(N_SEQ / 64, BATCH * NH), 256, 0, stream>>>(Qb, Kb, Vt, xb);

    // output projection -> f32 d_out
    gemm_mfma_kernel<false><<<dim3(EMB / 128, M_TOT / 128), 256, 0, stream>>>(
        xb, Wproj, proj_b, out, EMB, EMB);
}